// Round 6
// baseline (545.834 us; speedup 1.0000x reference)
//
#include <hip/hip_runtime.h>

#define B_  4
#define T_  2048
#define C_  1024
#define NH_ 16
#define DH_ 64

typedef __attribute__((ext_vector_type(8))) short bf16x8;
typedef __attribute__((ext_vector_type(4))) float f32x4;

__device__ __forceinline__ unsigned short f2bf(float f) {
  unsigned u = __builtin_bit_cast(unsigned, f);
  u += 0x7fffu + ((u >> 16) & 1u);          // RTNE
  return (unsigned short)(u >> 16);
}

// async global->LDS DMA, 16B per lane; LDS dest = uniform base + lane*16
__device__ __forceinline__ void gld16(const void* g, void* l) {
  __builtin_amdgcn_global_load_lds(
      (const __attribute__((address_space(1))) void*)g,
      (__attribute__((address_space(3))) void*)l, 16, 0, 0);
}

// ---------------- fp32 -> bf16 elementwise ----------------
__global__ void k_cvt(const float* __restrict__ x, unsigned short* __restrict__ o, int n) {
  int i = (blockIdx.x * 256 + threadIdx.x) * 4;
  if (i < n) {
    const float4 v = *reinterpret_cast<const float4*>(x + i);
    ushort4 u;
    u.x = f2bf(v.x); u.y = f2bf(v.y); u.z = f2bf(v.z); u.w = f2bf(v.w);
    *reinterpret_cast<ushort4*>(o + i) = u;
  }
}

// ---------------- fp32 [K][N] -> bf16 [N][K] transpose ----------------
__global__ void k_transpose(const float* __restrict__ w, unsigned short* __restrict__ wt,
                            int K, int N) {
  __shared__ float tile[32][33];
  int tx = threadIdx.x, ty = threadIdx.y;
  int n0 = blockIdx.x * 32, k0 = blockIdx.y * 32;
  #pragma unroll
  for (int j = 0; j < 32; j += 8)
    tile[ty + j][tx] = w[(size_t)(k0 + ty + j) * N + n0 + tx];
  __syncthreads();
  #pragma unroll
  for (int j = 0; j < 32; j += 8)
    wt[(size_t)(n0 + ty + j) * K + k0 + tx] = f2bf(tile[tx][ty + j]);
}

// ---------------- bf16 GEMM: 128x256 tile, 8-wave, 2-phase/K-tile pipeline ----
// (unchanged from round 3 — see comments there)
template <int EPI>
__global__ __launch_bounds__(512, 1)
void k_gemm(const unsigned short* __restrict__ A,
            const unsigned short* __restrict__ Bt,
            int M, int N, int K,
            float* __restrict__ outF,
            unsigned short* __restrict__ qb,
            unsigned short* __restrict__ kb,
            unsigned short* __restrict__ vbT,
            float* __restrict__ kout,
            float* __restrict__ vout) {
  __shared__ __align__(16) unsigned short SMEM[49152];   // 96 KB

  const int tid  = threadIdx.x;
  const int wave = tid >> 6;
  const int lane = tid & 63;
  const int l15  = lane & 15;
  const int quad = lane >> 4;
  const int wm   = (wave >> 2) * 64;
  const int wn   = (wave & 3) * 64;

  const int gx  = gridDim.x;
  const int lin = blockIdx.y * gx + blockIdx.x;
  const int cpx = (gx * gridDim.y) >> 3;
  const int sw  = (lin & 7) * cpx + (lin >> 3);
  const int m0  = (sw / gx) * 128;
  const int n0  = (sw % gx) * 256;

  const int cof0 = ((quad ^ (l15 & 7)) * 8);
  const int cof1 = cof0 ^ 32;

  f32x4 acc[4][4];
  #pragma unroll
  for (int i = 0; i < 4; i++)
    #pragma unroll
    for (int j = 0; j < 4; j++)
      acc[i][j] = f32x4{0.f, 0.f, 0.f, 0.f};

  auto stage_A = [&](int kt) {
    unsigned short* dst = SMEM + (kt & 1) * 8192;
    const unsigned short* src = A + (size_t)m0 * K + kt * 64;
    #pragma unroll
    for (int it = 0; it < 2; ++it) {
      int c0  = it * 512 + wave * 64;
      int c   = c0 + lane;
      int row = c >> 3;
      int scc = (c & 7) ^ (row & 7);
      gld16(src + (size_t)row * K + scc * 8, dst + c0 * 8);
    }
  };
  auto stage_B = [&](int kt, int h) {
    unsigned short* dst = SMEM + 16384 + (kt & 1) * 16384 + h * 8192;
    const unsigned short* src = Bt + (size_t)(n0 + h * 128) * K + kt * 64;
    #pragma unroll
    for (int it = 0; it < 2; ++it) {
      int c0  = it * 512 + wave * 64;
      int c   = c0 + lane;
      int row = c >> 3;
      int scc = (c & 7) ^ (row & 7);
      gld16(src + (size_t)row * K + scc * 8, dst + c0 * 8);
    }
  };

  const int NT = K >> 6;   // 16

  stage_A(0);
  stage_B(0, 0); stage_B(0, 1);
  stage_A(1);
  asm volatile("s_waitcnt vmcnt(2)" ::: "memory");
  __builtin_amdgcn_s_barrier();

  bf16x8 af[4][2], b0[2][2], b1[2][2];

  for (int t = 0; t < NT; ++t) {
    const unsigned short* Au = SMEM + (t & 1) * 8192;
    const unsigned short* Bu = SMEM + 16384 + (t & 1) * 16384;

    // ---------- phase 1: cols wn..wn+31 ----------
    #pragma unroll
    for (int mt = 0; mt < 4; mt++) {
      const unsigned short* r = Au + (wm + mt * 16 + l15) * 64;
      af[mt][0] = *reinterpret_cast<const bf16x8*>(r + cof0);
      af[mt][1] = *reinterpret_cast<const bf16x8*>(r + cof1);
    }
    #pragma unroll
    for (int nt = 0; nt < 2; nt++) {
      const unsigned short* r = Bu + (wn + nt * 16 + l15) * 64;
      b0[nt][0] = *reinterpret_cast<const bf16x8*>(r + cof0);
      b0[nt][1] = *reinterpret_cast<const bf16x8*>(r + cof1);
    }
    if (t + 1 < NT) stage_B(t + 1, 0);
    __builtin_amdgcn_s_barrier();
    asm volatile("s_waitcnt lgkmcnt(0)" ::: "memory");
    __builtin_amdgcn_sched_barrier(0);
    __builtin_amdgcn_s_setprio(1);
    #pragma unroll
    for (int mt = 0; mt < 4; mt++)
      #pragma unroll
      for (int nt = 0; nt < 2; nt++) {
        acc[mt][nt] = __builtin_amdgcn_mfma_f32_16x16x32_bf16(af[mt][0], b0[nt][0], acc[mt][nt], 0, 0, 0);
        acc[mt][nt] = __builtin_amdgcn_mfma_f32_16x16x32_bf16(af[mt][1], b0[nt][1], acc[mt][nt], 0, 0, 0);
      }
    __builtin_amdgcn_s_setprio(0);
    __builtin_amdgcn_s_barrier();

    // ---------- phase 2: cols wn+32..wn+63 ----------
    #pragma unroll
    for (int nt = 0; nt < 2; nt++) {
      const unsigned short* r = Bu + (wn + 32 + nt * 16 + l15) * 64;
      b1[nt][0] = *reinterpret_cast<const bf16x8*>(r + cof0);
      b1[nt][1] = *reinterpret_cast<const bf16x8*>(r + cof1);
    }
    if (t + 1 < NT) stage_B(t + 1, 1);
    if (t + 2 < NT) stage_A(t + 2);
    __builtin_amdgcn_s_barrier();
    asm volatile("s_waitcnt lgkmcnt(0)" ::: "memory");
    __builtin_amdgcn_sched_barrier(0);
    __builtin_amdgcn_s_setprio(1);
    #pragma unroll
    for (int mt = 0; mt < 4; mt++)
      #pragma unroll
      for (int nt = 0; nt < 2; nt++) {
        acc[mt][2 + nt] = __builtin_amdgcn_mfma_f32_16x16x32_bf16(af[mt][0], b1[nt][0], acc[mt][2 + nt], 0, 0, 0);
        acc[mt][2 + nt] = __builtin_amdgcn_mfma_f32_16x16x32_bf16(af[mt][1], b1[nt][1], acc[mt][2 + nt], 0, 0, 0);
      }
    __builtin_amdgcn_s_setprio(0);
    if (t + 2 < NT)      { asm volatile("s_waitcnt vmcnt(2)" ::: "memory"); }
    else if (t + 1 < NT) { asm volatile("s_waitcnt vmcnt(0)" ::: "memory"); }
    __builtin_amdgcn_s_barrier();
  }

  // ---------------- epilogue ----------------
  if constexpr (EPI == 1) {
    #pragma unroll
    for (int mt = 0; mt < 4; mt++)
      #pragma unroll
      for (int nt = 0; nt < 4; nt++)
        #pragma unroll
        for (int r = 0; r < 4; r++) {
          int gm = m0 + wm + mt * 16 + quad * 4 + r;
          int gn = n0 + wn + nt * 16 + l15;
          outF[(size_t)gm * N + gn] = acc[mt][nt][r];
        }
  } else {
    const int secb = n0 >> 10;     // block-uniform: 0=q, 1=k, 2=v
    if (secb == 2) {
      const int b      = m0 >> 11;
      const int t2base = m0 & 2047;
      const int h2base = (n0 - 2048) >> 6;
      #pragma unroll
      for (int mt = 0; mt < 4; mt++)
        #pragma unroll
        for (int nt = 0; nt < 4; nt++) {
          const int col  = wn + nt * 16 + l15;
          const int cn   = (n0 - 2048) + col;
          const int h2   = cn >> 6, d = cn & 63;
          #pragma unroll
          for (int r = 0; r < 4; r++) {
            float v = acc[mt][nt][r];
            int rowl = wm + mt * 16 + quad * 4 + r;
            int t2   = t2base + rowl;
            vout[(((size_t)(b * NH_ + h2)) * T_ + t2) * DH_ + d] = v;
            SMEM[col * 136 + rowl] = f2bf(v);
          }
        }
      __syncthreads();
      #pragma unroll
      for (int i = 0; i < 8; i++) {
        int chunk = i * 512 + tid;            // 4096 chunks = 256 cols x 16 tq
        int col = chunk >> 4, tq = chunk & 15;
        bf16x8 vv = *reinterpret_cast<const bf16x8*>(&SMEM[col * 136 + tq * 8]);
        int h2 = h2base + (col >> 6), d = col & 63;
        size_t idxT = (((size_t)(b * NH_ + h2)) * DH_ + d) * T_ + t2base + tq * 8;
        *reinterpret_cast<bf16x8*>(vbT + idxT) = vv;
      }
    } else {
      #pragma unroll
      for (int mt = 0; mt < 4; mt++)
        #pragma unroll
        for (int nt = 0; nt < 4; nt++)
          #pragma unroll
          for (int r = 0; r < 4; r++) {
            float v  = acc[mt][nt][r];
            int   gm = m0 + wm + mt * 16 + quad * 4 + r;
            int   gn = n0 + wn + nt * 16 + l15;
            int b = gm >> 11, t2 = gm & 2047;
            int cn = gn & 1023;
            int h2 = cn >> 6, d = cn & 63;
            size_t idxN = (((size_t)(b * NH_ + h2)) * T_ + t2) * DH_ + d;
            unsigned short bv = f2bf(v);
            if (secb == 0) { qb[idxN] = bv; }
            else           { kb[idxN] = bv; kout[idxN] = v; }
          }
    }
  }
}

// ---------------- flash attention, 64-row paired q-tiles ----------------
// grid: B*NH*16 blocks; block = q-tiles (pair, 31-pair), uniform 33 tile-units.
// 4 waves x 16 q-rows per phase. Fixed-offset softmax; l via MFMA vs ones.
// Double-buffered K/V (stage(t+1) at iter start, one vmcnt(0)+barrier at end).
// Ps [16][64] shorts per wave with XOR chunk swizzle: value (row q, 16B-chunk c)
// stored at chunk c ^ g(q), g(q) = (q&7) ^ 3*(q>>3). Bijective per row; write
// instrs spread 64 lanes over all 32 banks (2/bank free); b128 reads ~2/bank.
// LDS = 16K + 16K + 8K = 40960 B exactly -> 4 blocks/CU.
// Round 6: P->bf16 via proven f2bf (round-5's v_cvt_pk_bf16_f32 asm produced
// NaN — suspected partial dst write; do NOT reintroduce without isolation).
// Explicit lgkmcnt(0)+sched_barrier between Ps writes and pa reads, and a
// sched_barrier at p-body end (orders p=1 writes after p=0 reads).
__global__ __launch_bounds__(256, 4)
void k_attn(const unsigned short* __restrict__ qb,
            const unsigned short* __restrict__ kb,
            const unsigned short* __restrict__ vbT,
            unsigned short* __restrict__ ya) {
  __shared__ __align__(16) unsigned short Ks[2][64 * 64];   // K tiles [key][d], swizzled
  __shared__ __align__(16) unsigned short Vts[2][64 * 64];  // V^T tiles [d][key], swizzled
  __shared__ __align__(16) unsigned short Ps[4][16 * 64];   // P tiles, chunk-swizzled

  const int tid  = threadIdx.x;
  const int wave = tid >> 6;
  const int lane = tid & 63;
  const int l15  = lane & 15;
  const int quad = lane >> 4;

  const int blk  = blockIdx.x;
  const int pair = blk & 15;
  const int bh   = blk >> 4;            // b*16 + h
  const int q0p[2] = {pair * 64, (31 - pair) * 64};
  const int nkt[2] = {pair + 1, 32 - pair};
  const size_t base  = (size_t)bh * T_ * DH_;   // natural [t][d]
  const size_t baseT = (size_t)bh * DH_ * T_;   // transposed [d][t]

  const float CS = 0.180336880f;        // 0.125 * log2(e)
  const float PB = 17.3123404907f;      // 12 * log2(e) — fixed softmax offset

  const int sco0 = (quad ^ (l15 & 7)) * 8;   // K/V swizzled chunk offset, kf=0
  const int sco1 = sco0 ^ 32;                // kf=1

  // Ps swizzle lane constants (loop-invariant -> hoisted)
  unsigned short* Pw = Ps[wave];
  const int l7 = l15 & 7, hh = l15 >> 3;
  const int sB = (quad & 1) * 4;             // (row&7) high part, row = quad*4+r
  const int sC = 3 * (quad >> 1);            // 3*(row>>3)
  const int rsw = l7 ^ (3 * hh);             // g(l15) for the read side

  // Q fragments (A-layout), both phases: row = l15, k = quad*8+j
  bf16x8 qf[2][2];
  #pragma unroll
  for (int p = 0; p < 2; p++)
    #pragma unroll
    for (int kf = 0; kf < 2; kf++)
      qf[p][kf] = *reinterpret_cast<const bf16x8*>(
          qb + base + (size_t)(q0p[p] + wave * 16 + l15) * DH_ + kf * 32 + quad * 8);

  bf16x8 onesb;
  #pragma unroll
  for (int j = 0; j < 8; j++) onesb[j] = (short)0x3F80;   // bf16 1.0

  f32x4 of[2][4], ls[2];
  #pragma unroll
  for (int p = 0; p < 2; p++) {
    ls[p] = f32x4{0.f, 0.f, 0.f, 0.f};
    #pragma unroll
    for (int nt = 0; nt < 4; nt++)
      of[p][nt] = f32x4{0.f, 0.f, 0.f, 0.f};
  }

  // stage tile kt into buffer kt&1; 4 gld16/lane; inverse-swizzled global src
  auto stage = [&](int kt) {
    unsigned short* dk = Ks[kt & 1];
    unsigned short* dv = Vts[kt & 1];
    #pragma unroll
    for (int i = 0; i < 2; i++) {
      int c0  = (wave * 2 + i) * 64;     // uniform chunk base (512 chunks/tile)
      int c   = c0 + lane;
      int row = c >> 3;
      int sc  = (c & 7) ^ (row & 7);
      gld16(kb + base + (size_t)(kt * 64 + row) * 64 + sc * 8, dk + c0 * 8);
      gld16(vbT + baseT + (size_t)row * T_ + kt * 64 + sc * 8, dv + c0 * 8);
    }
  };

  const int NT = nkt[1];

  stage(0);
  asm volatile("s_waitcnt vmcnt(0)" ::: "memory");
  __builtin_amdgcn_s_barrier();

  for (int kt = 0; kt < NT; kt++) {
    if (kt + 1 < NT) stage(kt + 1);     // lands during this tile's compute

    const unsigned short* Ku = Ks[kt & 1];
    const unsigned short* Vu = Vts[kt & 1];
    bf16x8 bk[4][2], vbf[4][2];
    #pragma unroll
    for (int nt = 0; nt < 4; nt++) {
      const unsigned short* rk = Ku + (nt * 16 + l15) * 64;
      const unsigned short* rv = Vu + (nt * 16 + l15) * 64;
      bk[nt][0]  = *reinterpret_cast<const bf16x8*>(rk + sco0);
      bk[nt][1]  = *reinterpret_cast<const bf16x8*>(rk + sco1);
      vbf[nt][0] = *reinterpret_cast<const bf16x8*>(rv + sco0);
      vbf[nt][1] = *reinterpret_cast<const bf16x8*>(rv + sco1);
    }

    #pragma unroll
    for (int p = 0; p < 2; p++) {
      if (kt >= nkt[p]) continue;       // block-uniform

      f32x4 s[4];
      #pragma unroll
      for (int nt = 0; nt < 4; nt++) s[nt] = f32x4{0.f, 0.f, 0.f, 0.f};
      __builtin_amdgcn_s_setprio(1);
      #pragma unroll
      for (int nt = 0; nt < 4; nt++)
        #pragma unroll
        for (int kf = 0; kf < 2; kf++)
          s[nt] = __builtin_amdgcn_mfma_f32_16x16x32_bf16(qf[p][kf], bk[nt][kf], s[nt], 0, 0, 0);
      __builtin_amdgcn_s_setprio(0);

      if (kt == nkt[p] - 1) {           // diagonal tile only — wave-uniform
        #pragma unroll
        for (int nt = 0; nt < 4; nt++) {
          int gk = kt * 64 + nt * 16 + l15;
          #pragma unroll
          for (int r = 0; r < 4; r++) {
            int gq = q0p[p] + wave * 16 + quad * 4 + r;
            s[nt][r] = (gk <= gq) ? s[nt][r] : -3e38f;
          }
        }
      }

      // p = exp2(s*CS - PB); store swizzled b16 (proven f2bf path)
      #pragma unroll
      for (int nt = 0; nt < 4; nt++) {
        const int cb = 2 * nt + hh;     // logical 16B chunk of col nt*16+l15
        #pragma unroll
        for (int r = 0; r < 4; r++) {
          float pv = __builtin_amdgcn_exp2f(__builtin_fmaf(s[nt][r], CS, -PB));
          Pw[(quad * 4 + r) * 64 + ((cb ^ ((sB | r) ^ sC)) << 3) + l7] = f2bf(pv);
        }
      }
      asm volatile("s_waitcnt lgkmcnt(0)" ::: "memory");   // Ps writes landed
      __builtin_amdgcn_sched_barrier(0);                   // reads stay below

      // P back in A-layout (row = l15, chunk 4kf+quad, swizzled by rsw)
      bf16x8 pa[2];
      #pragma unroll
      for (int kf = 0; kf < 2; kf++)
        pa[kf] = *reinterpret_cast<const bf16x8*>(
            &Pw[l15 * 64 + (((4 * kf + quad) ^ rsw) << 3)]);
      __builtin_amdgcn_s_setprio(1);
      #pragma unroll
      for (int nt = 0; nt < 4; nt++)
        #pragma unroll
        for (int kf = 0; kf < 2; kf++)
          of[p][nt] = __builtin_amdgcn_mfma_f32_16x16x32_bf16(pa[kf], vbf[nt][kf], of[p][nt], 0, 0, 0);
      #pragma unroll
      for (int kf = 0; kf < 2; kf++)
        ls[p] = __builtin_amdgcn_mfma_f32_16x16x32_bf16(pa[kf], onesb, ls[p], 0, 0, 0);
      __builtin_amdgcn_s_setprio(0);
      __builtin_amdgcn_sched_barrier(0);                   // p=1 writes stay below p=0 reads
    }

    asm volatile("s_waitcnt vmcnt(0)" ::: "memory");   // t+1's DMA done (hidden)
    __builtin_amdgcn_s_barrier();                      // all reads of buf retired
  }

  // ---- epilogue: ya[b][t][h*64+d] = O / l ----
  const int b = bh >> 4, h = bh & 15;
  #pragma unroll
  for (int p = 0; p < 2; p++)
    #pragma unroll
    for (int r = 0; r < 4; r++) {
      int t = q0p[p] + wave * 16 + quad * 4 + r;
      float inv = 1.f / ls[p][r];
      #pragma unroll
      for (int nt = 0; nt < 4; nt++) {
        int col = h * DH_ + nt * 16 + l15;
        ya[((size_t)(b * T_ + t)) * C_ + col] = f2bf(of[p][nt][r] * inv);
      }
    }
}

extern "C" void kernel_launch(void* const* d_in, const int* in_sizes, int n_in,
                              void* d_out, int out_size, void* d_ws, size_t ws_size,
                              hipStream_t stream) {
  const float* x      = (const float*)d_in[0];
  const float* w_attn = (const float*)d_in[1];
  const float* w_proj = (const float*)d_in[2];

  float* y    = (float*)d_out;
  float* kout = y + (size_t)B_ * T_ * C_;
  float* vout = kout + (size_t)B_ * T_ * C_;

  char* ws = (char*)d_ws;
  const size_t xe = (size_t)B_ * T_ * C_;      // 8.4M elements
  unsigned short* xb  = (unsigned short*)ws;  ws += xe * 2;
  unsigned short* wab = (unsigned short*)ws;  ws += (size_t)3 * C_ * C_ * 2;
  unsigned short* wpb = (unsigned short*)ws;  ws += (size_t)C_ * C_ * 2;
  unsigned short* qbb = (unsigned short*)ws;  ws += xe * 2;
  unsigned short* kbb = (unsigned short*)ws;  ws += xe * 2;
  unsigned short* vbb = (unsigned short*)ws;  ws += xe * 2;   // holds V^T [b,h,d,t]
  unsigned short* ya  = xb;   // reuse: xb dead after qkv GEMM

  const int M = B_ * T_;

  k_cvt<<<(int)(xe / 4 / 256), 256, 0, stream>>>(x, xb, (int)xe);
  k_transpose<<<dim3(3 * C_ / 32, C_ / 32), dim3(32, 8), 0, stream>>>(w_attn, wab, C_, 3 * C_);
  k_transpose<<<dim3(C_ / 32, C_ / 32), dim3(32, 8), 0, stream>>>(w_proj, wpb, C_, C_);

  k_gemm<0><<<dim3(3 * C_ / 256, M / 128), 512, 0, stream>>>(
      xb, wab, M, 3 * C_, C_, nullptr, qbb, kbb, vbb, kout, vout);

  k_attn<<<dim3(B_ * NH_ * 16), 256, 0, stream>>>(qbb, kbb, vbb, ya);

  k_gemm<1><<<dim3(C_ / 256, M / 128), 512, 0, stream>>>(
      ya, wpb, M, C_, C_, y, nullptr, nullptr, nullptr, nullptr, nullptr);
}

// Round 7
// 323.209 us; speedup vs baseline: 1.6888x; 1.6888x over previous
//
#include <hip/hip_runtime.h>

#define B_  4
#define T_  2048
#define C_  1024
#define NH_ 16
#define DH_ 64

typedef __attribute__((ext_vector_type(8))) short bf16x8;
typedef __attribute__((ext_vector_type(4))) float f32x4;

__device__ __forceinline__ unsigned short f2bf(float f) {
  unsigned u = __builtin_bit_cast(unsigned, f);
  u += 0x7fffu + ((u >> 16) & 1u);          // RTNE
  return (unsigned short)(u >> 16);
}

// async global->LDS DMA, 16B per lane; LDS dest = uniform base + lane*16
__device__ __forceinline__ void gld16(const void* g, void* l) {
  __builtin_amdgcn_global_load_lds(
      (const __attribute__((address_space(1))) void*)g,
      (__attribute__((address_space(3))) void*)l, 16, 0, 0);
}

// ---------------- fp32 -> bf16 elementwise ----------------
__global__ void k_cvt(const float* __restrict__ x, unsigned short* __restrict__ o, int n) {
  int i = (blockIdx.x * 256 + threadIdx.x) * 4;
  if (i < n) {
    const float4 v = *reinterpret_cast<const float4*>(x + i);
    ushort4 u;
    u.x = f2bf(v.x); u.y = f2bf(v.y); u.z = f2bf(v.z); u.w = f2bf(v.w);
    *reinterpret_cast<ushort4*>(o + i) = u;
  }
}

// ---------------- fp32 [K][N] -> bf16 [N][K] transpose ----------------
__global__ void k_transpose(const float* __restrict__ w, unsigned short* __restrict__ wt,
                            int K, int N) {
  __shared__ float tile[32][33];
  int tx = threadIdx.x, ty = threadIdx.y;
  int n0 = blockIdx.x * 32, k0 = blockIdx.y * 32;
  #pragma unroll
  for (int j = 0; j < 32; j += 8)
    tile[ty + j][tx] = w[(size_t)(k0 + ty + j) * N + n0 + tx];
  __syncthreads();
  #pragma unroll
  for (int j = 0; j < 32; j += 8)
    wt[(size_t)(n0 + ty + j) * K + k0 + tx] = f2bf(tile[tx][ty + j]);
}

// ---------------- bf16 GEMM: 128x256 tile, 8-wave, 2-phase/K-tile pipeline ----
// (unchanged from round 3 — see comments there)
template <int EPI>
__global__ __launch_bounds__(512, 1)
void k_gemm(const unsigned short* __restrict__ A,
            const unsigned short* __restrict__ Bt,
            int M, int N, int K,
            float* __restrict__ outF,
            unsigned short* __restrict__ qb,
            unsigned short* __restrict__ kb,
            unsigned short* __restrict__ vbT,
            float* __restrict__ kout,
            float* __restrict__ vout) {
  __shared__ __align__(16) unsigned short SMEM[49152];   // 96 KB

  const int tid  = threadIdx.x;
  const int wave = tid >> 6;
  const int lane = tid & 63;
  const int l15  = lane & 15;
  const int quad = lane >> 4;
  const int wm   = (wave >> 2) * 64;
  const int wn   = (wave & 3) * 64;

  const int gx  = gridDim.x;
  const int lin = blockIdx.y * gx + blockIdx.x;
  const int cpx = (gx * gridDim.y) >> 3;
  const int sw  = (lin & 7) * cpx + (lin >> 3);
  const int m0  = (sw / gx) * 128;
  const int n0  = (sw % gx) * 256;

  const int cof0 = ((quad ^ (l15 & 7)) * 8);
  const int cof1 = cof0 ^ 32;

  f32x4 acc[4][4];
  #pragma unroll
  for (int i = 0; i < 4; i++)
    #pragma unroll
    for (int j = 0; j < 4; j++)
      acc[i][j] = f32x4{0.f, 0.f, 0.f, 0.f};

  auto stage_A = [&](int kt) {
    unsigned short* dst = SMEM + (kt & 1) * 8192;
    const unsigned short* src = A + (size_t)m0 * K + kt * 64;
    #pragma unroll
    for (int it = 0; it < 2; ++it) {
      int c0  = it * 512 + wave * 64;
      int c   = c0 + lane;
      int row = c >> 3;
      int scc = (c & 7) ^ (row & 7);
      gld16(src + (size_t)row * K + scc * 8, dst + c0 * 8);
    }
  };
  auto stage_B = [&](int kt, int h) {
    unsigned short* dst = SMEM + 16384 + (kt & 1) * 16384 + h * 8192;
    const unsigned short* src = Bt + (size_t)(n0 + h * 128) * K + kt * 64;
    #pragma unroll
    for (int it = 0; it < 2; ++it) {
      int c0  = it * 512 + wave * 64;
      int c   = c0 + lane;
      int row = c >> 3;
      int scc = (c & 7) ^ (row & 7);
      gld16(src + (size_t)row * K + scc * 8, dst + c0 * 8);
    }
  };

  const int NT = K >> 6;   // 16

  stage_A(0);
  stage_B(0, 0); stage_B(0, 1);
  stage_A(1);
  asm volatile("s_waitcnt vmcnt(2)" ::: "memory");
  __builtin_amdgcn_s_barrier();

  bf16x8 af[4][2], b0[2][2], b1[2][2];

  for (int t = 0; t < NT; ++t) {
    const unsigned short* Au = SMEM + (t & 1) * 8192;
    const unsigned short* Bu = SMEM + 16384 + (t & 1) * 16384;

    // ---------- phase 1: cols wn..wn+31 ----------
    #pragma unroll
    for (int mt = 0; mt < 4; mt++) {
      const unsigned short* r = Au + (wm + mt * 16 + l15) * 64;
      af[mt][0] = *reinterpret_cast<const bf16x8*>(r + cof0);
      af[mt][1] = *reinterpret_cast<const bf16x8*>(r + cof1);
    }
    #pragma unroll
    for (int nt = 0; nt < 2; nt++) {
      const unsigned short* r = Bu + (wn + nt * 16 + l15) * 64;
      b0[nt][0] = *reinterpret_cast<const bf16x8*>(r + cof0);
      b0[nt][1] = *reinterpret_cast<const bf16x8*>(r + cof1);
    }
    if (t + 1 < NT) stage_B(t + 1, 0);
    __builtin_amdgcn_s_barrier();
    asm volatile("s_waitcnt lgkmcnt(0)" ::: "memory");
    __builtin_amdgcn_sched_barrier(0);
    __builtin_amdgcn_s_setprio(1);
    #pragma unroll
    for (int mt = 0; mt < 4; mt++)
      #pragma unroll
      for (int nt = 0; nt < 2; nt++) {
        acc[mt][nt] = __builtin_amdgcn_mfma_f32_16x16x32_bf16(af[mt][0], b0[nt][0], acc[mt][nt], 0, 0, 0);
        acc[mt][nt] = __builtin_amdgcn_mfma_f32_16x16x32_bf16(af[mt][1], b0[nt][1], acc[mt][nt], 0, 0, 0);
      }
    __builtin_amdgcn_s_setprio(0);
    __builtin_amdgcn_s_barrier();

    // ---------- phase 2: cols wn+32..wn+63 ----------
    #pragma unroll
    for (int nt = 0; nt < 2; nt++) {
      const unsigned short* r = Bu + (wn + 32 + nt * 16 + l15) * 64;
      b1[nt][0] = *reinterpret_cast<const bf16x8*>(r + cof0);
      b1[nt][1] = *reinterpret_cast<const bf16x8*>(r + cof1);
    }
    if (t + 1 < NT) stage_B(t + 1, 1);
    if (t + 2 < NT) stage_A(t + 2);
    __builtin_amdgcn_s_barrier();
    asm volatile("s_waitcnt lgkmcnt(0)" ::: "memory");
    __builtin_amdgcn_sched_barrier(0);
    __builtin_amdgcn_s_setprio(1);
    #pragma unroll
    for (int mt = 0; mt < 4; mt++)
      #pragma unroll
      for (int nt = 0; nt < 2; nt++) {
        acc[mt][2 + nt] = __builtin_amdgcn_mfma_f32_16x16x32_bf16(af[mt][0], b1[nt][0], acc[mt][2 + nt], 0, 0, 0);
        acc[mt][2 + nt] = __builtin_amdgcn_mfma_f32_16x16x32_bf16(af[mt][1], b1[nt][1], acc[mt][2 + nt], 0, 0, 0);
      }
    __builtin_amdgcn_s_setprio(0);
    if (t + 2 < NT)      { asm volatile("s_waitcnt vmcnt(2)" ::: "memory"); }
    else if (t + 1 < NT) { asm volatile("s_waitcnt vmcnt(0)" ::: "memory"); }
    __builtin_amdgcn_s_barrier();
  }

  // ---------------- epilogue ----------------
  if constexpr (EPI == 1) {
    #pragma unroll
    for (int mt = 0; mt < 4; mt++)
      #pragma unroll
      for (int nt = 0; nt < 4; nt++)
        #pragma unroll
        for (int r = 0; r < 4; r++) {
          int gm = m0 + wm + mt * 16 + quad * 4 + r;
          int gn = n0 + wn + nt * 16 + l15;
          outF[(size_t)gm * N + gn] = acc[mt][nt][r];
        }
  } else {
    const int secb = n0 >> 10;     // block-uniform: 0=q, 1=k, 2=v
    if (secb == 2) {
      const int b      = m0 >> 11;
      const int t2base = m0 & 2047;
      const int h2base = (n0 - 2048) >> 6;
      #pragma unroll
      for (int mt = 0; mt < 4; mt++)
        #pragma unroll
        for (int nt = 0; nt < 4; nt++) {
          const int col  = wn + nt * 16 + l15;
          const int cn   = (n0 - 2048) + col;
          const int h2   = cn >> 6, d = cn & 63;
          #pragma unroll
          for (int r = 0; r < 4; r++) {
            float v = acc[mt][nt][r];
            int rowl = wm + mt * 16 + quad * 4 + r;
            int t2   = t2base + rowl;
            vout[(((size_t)(b * NH_ + h2)) * T_ + t2) * DH_ + d] = v;
            SMEM[col * 136 + rowl] = f2bf(v);
          }
        }
      __syncthreads();
      #pragma unroll
      for (int i = 0; i < 8; i++) {
        int chunk = i * 512 + tid;            // 4096 chunks = 256 cols x 16 tq
        int col = chunk >> 4, tq = chunk & 15;
        bf16x8 vv = *reinterpret_cast<const bf16x8*>(&SMEM[col * 136 + tq * 8]);
        int h2 = h2base + (col >> 6), d = col & 63;
        size_t idxT = (((size_t)(b * NH_ + h2)) * DH_ + d) * T_ + t2base + tq * 8;
        *reinterpret_cast<bf16x8*>(vbT + idxT) = vv;
      }
    } else {
      #pragma unroll
      for (int mt = 0; mt < 4; mt++)
        #pragma unroll
        for (int nt = 0; nt < 4; nt++)
          #pragma unroll
          for (int r = 0; r < 4; r++) {
            float v  = acc[mt][nt][r];
            int   gm = m0 + wm + mt * 16 + quad * 4 + r;
            int   gn = n0 + wn + nt * 16 + l15;
            int b = gm >> 11, t2 = gm & 2047;
            int cn = gn & 1023;
            int h2 = cn >> 6, d = cn & 63;
            size_t idxN = (((size_t)(b * NH_ + h2)) * T_ + t2) * DH_ + d;
            unsigned short bv = f2bf(v);
            if (secb == 0) { qb[idxN] = bv; }
            else           { kb[idxN] = bv; kout[idxN] = v; }
          }
    }
  }
}

// ---------------- flash attention, 64-row paired q-tiles ----------------
// grid: B*NH*16 blocks. XCD co-location remap: xcd = blk&7, pair = (blk>>3)&15,
// bh = (blk>>7)*8 + xcd  -> all 16 pair-blocks of a (b,h) land on ONE XCD
// (assuming round-robin wg->XCD dispatch; perf heuristic only). 8 bh/XCD x
// 512 KB KV = 4 MB = one XCD L2 -> KV streams become L2 hits.
// 4 waves x 16 q-rows per phase. Fixed-offset softmax; l via MFMA vs ones.
// Double-buffered K/V (stage(t+1) at iter start, one vmcnt(0)+barrier at end).
// Ps [16][64] shorts per wave, XOR chunk swizzle g(q) = (q&7) ^ 3*(q>>3).
// LDS = 40960 B. launch_bounds(256,3): (256,4) round-6 regression = VGPR
// budget 128 -> massive scratch spill (1.4 GB/dispatch). DO NOT raise again.
// P->bf16 via proven f2bf (round-5 v_cvt_pk_bf16_f32 asm gave NaN).
__global__ __launch_bounds__(256, 3)
void k_attn(const unsigned short* __restrict__ qb,
            const unsigned short* __restrict__ kb,
            const unsigned short* __restrict__ vbT,
            unsigned short* __restrict__ ya) {
  __shared__ __align__(16) unsigned short Ks[2][64 * 64];   // K tiles [key][d], swizzled
  __shared__ __align__(16) unsigned short Vts[2][64 * 64];  // V^T tiles [d][key], swizzled
  __shared__ __align__(16) unsigned short Ps[4][16 * 64];   // P tiles, chunk-swizzled

  const int tid  = threadIdx.x;
  const int wave = tid >> 6;
  const int lane = tid & 63;
  const int l15  = lane & 15;
  const int quad = lane >> 4;

  const int blk  = blockIdx.x;
  const int pair = (blk >> 3) & 15;
  const int bh   = ((blk >> 7) << 3) | (blk & 7);   // b*16 + h, XCD-co-located
  const int q0p[2] = {pair * 64, (31 - pair) * 64};
  const int nkt[2] = {pair + 1, 32 - pair};
  const size_t base  = (size_t)bh * T_ * DH_;   // natural [t][d]
  const size_t baseT = (size_t)bh * DH_ * T_;   // transposed [d][t]

  const float CS = 0.180336880f;        // 0.125 * log2(e)
  const float PB = 17.3123404907f;      // 12 * log2(e) — fixed softmax offset

  const int sco0 = (quad ^ (l15 & 7)) * 8;   // K/V swizzled chunk offset, kf=0
  const int sco1 = sco0 ^ 32;                // kf=1

  // Ps swizzle lane constants (loop-invariant -> hoisted)
  unsigned short* Pw = Ps[wave];
  const int l7 = l15 & 7, hh = l15 >> 3;
  const int sB = (quad & 1) * 4;             // (row&7) high part, row = quad*4+r
  const int sC = 3 * (quad >> 1);            // 3*(row>>3)
  const int rsw = l7 ^ (3 * hh);             // g(l15) for the read side

  // Q fragments (A-layout), both phases: row = l15, k = quad*8+j
  bf16x8 qf[2][2];
  #pragma unroll
  for (int p = 0; p < 2; p++)
    #pragma unroll
    for (int kf = 0; kf < 2; kf++)
      qf[p][kf] = *reinterpret_cast<const bf16x8*>(
          qb + base + (size_t)(q0p[p] + wave * 16 + l15) * DH_ + kf * 32 + quad * 8);

  bf16x8 onesb;
  #pragma unroll
  for (int j = 0; j < 8; j++) onesb[j] = (short)0x3F80;   // bf16 1.0

  f32x4 of[2][4], ls[2];
  #pragma unroll
  for (int p = 0; p < 2; p++) {
    ls[p] = f32x4{0.f, 0.f, 0.f, 0.f};
    #pragma unroll
    for (int nt = 0; nt < 4; nt++)
      of[p][nt] = f32x4{0.f, 0.f, 0.f, 0.f};
  }

  // stage tile kt into buffer kt&1; 4 gld16/lane; inverse-swizzled global src
  auto stage = [&](int kt) {
    unsigned short* dk = Ks[kt & 1];
    unsigned short* dv = Vts[kt & 1];
    #pragma unroll
    for (int i = 0; i < 2; i++) {
      int c0  = (wave * 2 + i) * 64;     // uniform chunk base (512 chunks/tile)
      int c   = c0 + lane;
      int row = c >> 3;
      int sc  = (c & 7) ^ (row & 7);
      gld16(kb + base + (size_t)(kt * 64 + row) * 64 + sc * 8, dk + c0 * 8);
      gld16(vbT + baseT + (size_t)row * T_ + kt * 64 + sc * 8, dv + c0 * 8);
    }
  };

  const int NT = nkt[1];

  stage(0);
  asm volatile("s_waitcnt vmcnt(0)" ::: "memory");
  __builtin_amdgcn_s_barrier();

  for (int kt = 0; kt < NT; kt++) {
    if (kt + 1 < NT) stage(kt + 1);     // lands during this tile's compute

    const unsigned short* Ku = Ks[kt & 1];
    const unsigned short* Vu = Vts[kt & 1];
    bf16x8 bk[4][2], vbf[4][2];
    #pragma unroll
    for (int nt = 0; nt < 4; nt++) {
      const unsigned short* rk = Ku + (nt * 16 + l15) * 64;
      const unsigned short* rv = Vu + (nt * 16 + l15) * 64;
      bk[nt][0]  = *reinterpret_cast<const bf16x8*>(rk + sco0);
      bk[nt][1]  = *reinterpret_cast<const bf16x8*>(rk + sco1);
      vbf[nt][0] = *reinterpret_cast<const bf16x8*>(rv + sco0);
      vbf[nt][1] = *reinterpret_cast<const bf16x8*>(rv + sco1);
    }

    #pragma unroll
    for (int p = 0; p < 2; p++) {
      if (kt >= nkt[p]) continue;       // block-uniform

      f32x4 s[4];
      #pragma unroll
      for (int nt = 0; nt < 4; nt++) s[nt] = f32x4{0.f, 0.f, 0.f, 0.f};
      __builtin_amdgcn_s_setprio(1);
      #pragma unroll
      for (int nt = 0; nt < 4; nt++)
        #pragma unroll
        for (int kf = 0; kf < 2; kf++)
          s[nt] = __builtin_amdgcn_mfma_f32_16x16x32_bf16(qf[p][kf], bk[nt][kf], s[nt], 0, 0, 0);
      __builtin_amdgcn_s_setprio(0);

      if (kt == nkt[p] - 1) {           // diagonal tile only — wave-uniform
        #pragma unroll
        for (int nt = 0; nt < 4; nt++) {
          int gk = kt * 64 + nt * 16 + l15;
          #pragma unroll
          for (int r = 0; r < 4; r++) {
            int gq = q0p[p] + wave * 16 + quad * 4 + r;
            s[nt][r] = (gk <= gq) ? s[nt][r] : -3e38f;
          }
        }
      }

      // p = exp2(s*CS - PB); store swizzled b16 (proven f2bf path)
      #pragma unroll
      for (int nt = 0; nt < 4; nt++) {
        const int cb = 2 * nt + hh;     // logical 16B chunk of col nt*16+l15
        #pragma unroll
        for (int r = 0; r < 4; r++) {
          float pv = __builtin_amdgcn_exp2f(__builtin_fmaf(s[nt][r], CS, -PB));
          Pw[(quad * 4 + r) * 64 + ((cb ^ ((sB | r) ^ sC)) << 3) + l7] = f2bf(pv);
        }
      }
      asm volatile("s_waitcnt lgkmcnt(0)" ::: "memory");   // Ps writes landed
      __builtin_amdgcn_sched_barrier(0);                   // reads stay below

      // P back in A-layout (row = l15, chunk 4kf+quad, swizzled by rsw)
      bf16x8 pa[2];
      #pragma unroll
      for (int kf = 0; kf < 2; kf++)
        pa[kf] = *reinterpret_cast<const bf16x8*>(
            &Pw[l15 * 64 + (((4 * kf + quad) ^ rsw) << 3)]);
      __builtin_amdgcn_s_setprio(1);
      #pragma unroll
      for (int nt = 0; nt < 4; nt++)
        #pragma unroll
        for (int kf = 0; kf < 2; kf++)
          of[p][nt] = __builtin_amdgcn_mfma_f32_16x16x32_bf16(pa[kf], vbf[nt][kf], of[p][nt], 0, 0, 0);
      #pragma unroll
      for (int kf = 0; kf < 2; kf++)
        ls[p] = __builtin_amdgcn_mfma_f32_16x16x32_bf16(pa[kf], onesb, ls[p], 0, 0, 0);
      __builtin_amdgcn_s_setprio(0);
      __builtin_amdgcn_sched_barrier(0);                   // p=1 writes stay below p=0 reads
    }

    asm volatile("s_waitcnt vmcnt(0)" ::: "memory");   // t+1's DMA done (hidden)
    __builtin_amdgcn_s_barrier();                      // all reads of buf retired
  }

  // ---- epilogue: ya[b][t][h*64+d] = O / l ----
  const int b = bh >> 4, h = bh & 15;
  #pragma unroll
  for (int p = 0; p < 2; p++)
    #pragma unroll
    for (int r = 0; r < 4; r++) {
      int t = q0p[p] + wave * 16 + quad * 4 + r;
      float inv = 1.f / ls[p][r];
      #pragma unroll
      for (int nt = 0; nt < 4; nt++) {
        int col = h * DH_ + nt * 16 + l15;
        ya[((size_t)(b * T_ + t)) * C_ + col] = f2bf(of[p][nt][r] * inv);
      }
    }
}

extern "C" void kernel_launch(void* const* d_in, const int* in_sizes, int n_in,
                              void* d_out, int out_size, void* d_ws, size_t ws_size,
                              hipStream_t stream) {
  const float* x      = (const float*)d_in[0];
  const float* w_attn = (const float*)d_in[1];
  const float* w_proj = (const float*)d_in[2];

  float* y    = (float*)d_out;
  float* kout = y + (size_t)B_ * T_ * C_;
  float* vout = kout + (size_t)B_ * T_ * C_;

  char* ws = (char*)d_ws;
  const size_t xe = (size_t)B_ * T_ * C_;      // 8.4M elements
  unsigned short* xb  = (unsigned short*)ws;  ws += xe * 2;
  unsigned short* wab = (unsigned short*)ws;  ws += (size_t)3 * C_ * C_ * 2;
  unsigned short* wpb = (unsigned short*)ws;  ws += (size_t)C_ * C_ * 2;
  unsigned short* qbb = (unsigned short*)ws;  ws += xe * 2;
  unsigned short* kbb = (unsigned short*)ws;  ws += xe * 2;
  unsigned short* vbb = (unsigned short*)ws;  ws += xe * 2;   // holds V^T [b,h,d,t]
  unsigned short* ya  = xb;   // reuse: xb dead after qkv GEMM

  const int M = B_ * T_;

  k_cvt<<<(int)(xe / 4 / 256), 256, 0, stream>>>(x, xb, (int)xe);
  k_transpose<<<dim3(3 * C_ / 32, C_ / 32), dim3(32, 8), 0, stream>>>(w_attn, wab, C_, 3 * C_);
  k_transpose<<<dim3(C_ / 32, C_ / 32), dim3(32, 8), 0, stream>>>(w_proj, wpb, C_, C_);

  k_gemm<0><<<dim3(3 * C_ / 256, M / 128), 512, 0, stream>>>(
      xb, wab, M, 3 * C_, C_, nullptr, qbb, kbb, vbb, kout, vout);

  k_attn<<<dim3(B_ * NH_ * 16), 256, 0, stream>>>(qbb, kbb, vbb, ya);

  k_gemm<1><<<dim3(C_ / 256, M / 128), 512, 0, stream>>>(
      ya, wpb, M, C_, C_, y, nullptr, nullptr, nullptr, nullptr, nullptr);
}